// Round 1
// baseline (75.494 us; speedup 1.0000x reference)
//
#include <hip/hip_runtime.h>

// Closed-form quanvolution:
//   per wire w: z_w = cos(alpha_w)*cos(beta_w)*cos(theta_w) - sin(beta_w)*sin(theta_w)
//   (Rz drops out of Z-expectations; CNOT chain 0->1->2->3 makes output bits
//    cumulative XORs, so <Z_w> = prod_{k<=w} z_k for a product state)
//   out = z0*(W0 + z1*(W1 + z2*(W2 + z3*W3)))
//
// v2: the 8 gate constants (cos(a)*cos(b), sin(b) per wire) and the 4 weights
// are batch-invariant. Previously every one of the 802816 threads recomputed
// them with 12 quarter-rate transcendental ops (~30% of per-wave issue).
// A 1-thread prologue now evaluates them once into the workspace; the main
// kernel reads them back as wave-uniform scalar loads.

__global__ void quanv_prologue(const float* __restrict__ params,
                               const float* __restrict__ Wm,
                               float* __restrict__ c) {
    // ca_w = cos(alpha_w)*cos(beta_w);  sb_w = sin(beta_w)
    c[0] = __cosf(params[0]) * __cosf(params[1]);
    c[1] = __cosf(params[3]) * __cosf(params[4]);
    c[2] = __cosf(params[6]) * __cosf(params[7]);
    c[3] = __cosf(params[9]) * __cosf(params[10]);
    c[4] = __sinf(params[1]);
    c[5] = __sinf(params[4]);
    c[6] = __sinf(params[7]);
    c[7] = __sinf(params[10]);
    c[8]  = Wm[0];
    c[9]  = Wm[1];
    c[10] = Wm[2];
    c[11] = Wm[3];
}

__global__ __launch_bounds__(256) void quanv_kernel(
    const float* __restrict__ x,
    const float* __restrict__ C,   // 12 precomputed constants in workspace
    float* __restrict__ out,
    int total)   // total = B * 98  (14 patch-rows * 7 float4-pairs per image)
{
    int t = blockIdx.x * blockDim.x + threadIdx.x;
    if (t >= total) return;

    int b  = t / 98;       // image
    int r  = t - b * 98;
    int i  = r / 7;        // patch row 0..13
    int p2 = r - i * 7;    // pair of patch columns 0..6

    // Coalesced, 16B-aligned loads of the two image rows feeding this patch pair.
    const float* base = x + (size_t)b * 784 + 56 * i;   // row 2i start
    float4 r0 = reinterpret_cast<const float4*>(base)[p2];
    float4 r1 = reinterpret_cast<const float4*>(base + 28)[p2];

    // Wave-uniform constants -> scalar loads, zero VALU cost.
    float ca0 = C[0], ca1 = C[1], ca2 = C[2], ca3 = C[3];
    float sb0 = C[4], sb1 = C[5], sb2 = C[6], sb3 = C[7];
    float w0  = C[8], w1  = C[9], w2  = C[10], w3 = C[11];

    float s, c;

    // Patch 0: thetas = r0.x (wire0), r0.y (wire1), r1.x (wire2), r1.y (wire3)
    __sincosf(r0.x, &s, &c); float z0 = ca0 * c - sb0 * s;
    __sincosf(r0.y, &s, &c); float z1 = ca1 * c - sb1 * s;
    __sincosf(r1.x, &s, &c); float z2 = ca2 * c - sb2 * s;
    __sincosf(r1.y, &s, &c); float z3 = ca3 * c - sb3 * s;
    float res0 = z0 * (w0 + z1 * (w1 + z2 * (w2 + z3 * w3)));

    // Patch 1: thetas = r0.z, r0.w, r1.z, r1.w
    __sincosf(r0.z, &s, &c); float y0 = ca0 * c - sb0 * s;
    __sincosf(r0.w, &s, &c); float y1 = ca1 * c - sb1 * s;
    __sincosf(r1.z, &s, &c); float y2 = ca2 * c - sb2 * s;
    __sincosf(r1.w, &s, &c); float y3 = ca3 * c - sb3 * s;
    float res1 = y0 * (w0 + y1 * (w1 + y2 * (w2 + y3 * w3)));

    *reinterpret_cast<float2*>(out + (size_t)b * 196 + i * 14 + 2 * p2) =
        make_float2(res0, res1);
}

extern "C" void kernel_launch(void* const* d_in, const int* in_sizes, int n_in,
                              void* d_out, int out_size, void* d_ws, size_t ws_size,
                              hipStream_t stream) {
    const float* x      = (const float*)d_in[0];
    const float* params = (const float*)d_in[1];
    const float* W      = (const float*)d_in[2];
    float* out          = (float*)d_out;
    float* C            = (float*)d_ws;   // 12 floats

    quanv_prologue<<<1, 1, 0, stream>>>(params, W, C);

    int B     = in_sizes[0] / 784;   // (B,1,28,28)
    int total = B * 98;              // 2 patches per thread
    int block = 256;
    int grid  = (total + block - 1) / block;
    quanv_kernel<<<grid, block, 0, stream>>>(x, C, out, total);
}

// Round 3
// 73.478 us; speedup vs baseline: 1.0274x; 1.0274x over previous
//
#include <hip/hip_runtime.h>

// Closed-form quanvolution:
//   per wire w: z_w = cos(alpha_w)*cos(beta_w)*cos(theta_w) - sin(beta_w)*sin(theta_w)
//   (Rz drops out of Z-expectations; CNOT chain 0->1->2->3 makes output bits
//    cumulative XORs, so <Z_w> = prod_{k<=w} z_k for a product state)
//   out = z0*(W0 + z1*(W1 + z2*(W2 + z3*W3)))
//
// v4: v3's lane-parallel uniform-constant evaluation, with the readlane bug
// fixed: __builtin_amdgcn_readlane takes int — v3 passed a float, which did a
// VALUE conversion (cvt_i32_f32) instead of a bitcast and destroyed the
// constants (absmax 2.84). Bitcast via __float_as_int/__int_as_float.
// Per-wave transcendentals: 2 uniform + 16 per-patch sincos per thread.

__device__ __forceinline__ float lane_bcast(float v, int l) {
    return __int_as_float(__builtin_amdgcn_readlane(__float_as_int(v), l));
}

__global__ __launch_bounds__(256) void quanv_kernel(
    const float* __restrict__ x,
    const float* __restrict__ params,
    const float* __restrict__ Wm,
    float* __restrict__ out,
    int total)   // total = B * 98  (14 patch-rows * 7 float4-pairs per image)
{
    // ---- Lane-parallel wave-uniform constants -------------------------------
    // lane l: w = l&3, g = l>>2.  g==0 -> cos(params[3w])   (cosA_w)
    //                             g==1 -> cos(params[3w+1]) (cosB_w)
    //                             g==2 -> sin(params[3w+1]) (sinB_w)
    int lane = threadIdx.x & 63;
    int wsel = lane & 3;
    int g    = lane >> 2;
    int pidx = 3 * wsel + (g == 0 ? 0 : 1);      // <= 10 for all lanes
    float p  = params[pidx];
    float cv = __cosf(p);
    float sv = __sinf(p);
    float val = (g == 2) ? sv : cv;              // lanes g>=3 unused

    float cA0 = lane_bcast(val, 0);
    float cA1 = lane_bcast(val, 1);
    float cA2 = lane_bcast(val, 2);
    float cA3 = lane_bcast(val, 3);
    float cB0 = lane_bcast(val, 4);
    float cB1 = lane_bcast(val, 5);
    float cB2 = lane_bcast(val, 6);
    float cB3 = lane_bcast(val, 7);
    float sb0 = lane_bcast(val, 8);
    float sb1 = lane_bcast(val, 9);
    float sb2 = lane_bcast(val, 10);
    float sb3 = lane_bcast(val, 11);

    float ca0 = cA0 * cB0, ca1 = cA1 * cB1, ca2 = cA2 * cB2, ca3 = cA3 * cB3;
    float w0 = Wm[0], w1 = Wm[1], w2 = Wm[2], w3 = Wm[3];  // uniform -> s_load

    int t = blockIdx.x * blockDim.x + threadIdx.x;
    if (t >= total) return;   // total = B*98 is an exact multiple of 256; no tail

    int b  = t / 98;       // image
    int r  = t - b * 98;
    int i  = r / 7;        // patch row 0..13
    int p2 = r - i * 7;    // pair of patch columns 0..6

    // Coalesced, 16B-aligned loads of the two image rows feeding this patch pair.
    const float* base = x + (size_t)b * 784 + 56 * i;   // row 2i start
    float4 r0 = reinterpret_cast<const float4*>(base)[p2];
    float4 r1 = reinterpret_cast<const float4*>(base + 28)[p2];

    float s, c;

    // Patch 0: thetas = r0.x (wire0), r0.y (wire1), r1.x (wire2), r1.y (wire3)
    __sincosf(r0.x, &s, &c); float z0 = ca0 * c - sb0 * s;
    __sincosf(r0.y, &s, &c); float z1 = ca1 * c - sb1 * s;
    __sincosf(r1.x, &s, &c); float z2 = ca2 * c - sb2 * s;
    __sincosf(r1.y, &s, &c); float z3 = ca3 * c - sb3 * s;
    float res0 = z0 * (w0 + z1 * (w1 + z2 * (w2 + z3 * w3)));

    // Patch 1: thetas = r0.z, r0.w, r1.z, r1.w
    __sincosf(r0.z, &s, &c); float y0 = ca0 * c - sb0 * s;
    __sincosf(r0.w, &s, &c); float y1 = ca1 * c - sb1 * s;
    __sincosf(r1.z, &s, &c); float y2 = ca2 * c - sb2 * s;
    __sincosf(r1.w, &s, &c); float y3 = ca3 * c - sb3 * s;
    float res1 = y0 * (w0 + y1 * (w1 + y2 * (w2 + y3 * w3)));

    *reinterpret_cast<float2*>(out + (size_t)b * 196 + i * 14 + 2 * p2) =
        make_float2(res0, res1);
}

extern "C" void kernel_launch(void* const* d_in, const int* in_sizes, int n_in,
                              void* d_out, int out_size, void* d_ws, size_t ws_size,
                              hipStream_t stream) {
    const float* x      = (const float*)d_in[0];
    const float* params = (const float*)d_in[1];
    const float* W      = (const float*)d_in[2];
    float* out          = (float*)d_out;

    int B     = in_sizes[0] / 784;   // (B,1,28,28)
    int total = B * 98;              // 2 patches per thread
    int block = 256;
    int grid  = (total + block - 1) / block;
    quanv_kernel<<<grid, block, 0, stream>>>(x, params, W, out, total);
}